// Round 14
// baseline (1322.946 us; speedup 1.0000x reference)
//
#include <hip/hip_runtime.h>
#include <stdint.h>

typedef unsigned short ushort_t;
typedef __attribute__((ext_vector_type(8))) __bf16 bf16x8;
typedef __attribute__((ext_vector_type(4))) float f32x4;

#define B_SZ 16384
#define SEQ 50
#define RAWF 109
#define ROWLEN (SEQ * RAWF)      // 5450 floats per row
#define EMB 20
#define DFEAT 128
#define H 512
#define H4 2048
#define NBLK 10
#define OUTD 20

__device__ __forceinline__ ushort_t f2bf(float f) {
    union { float f; uint32_t u; } v; v.f = f;
    uint32_t r = (v.u + 0x7fffu + ((v.u >> 16) & 1u)) >> 16;
    return (ushort_t)r;
}

__device__ __forceinline__ void glds16(const ushort_t* src, ushort_t* dst) {
    __builtin_amdgcn_global_load_lds(
        (const __attribute__((address_space(1))) void*)src,
        (__attribute__((address_space(3))) void*)dst, 16, 0, 0);
}

// ---------------- weight transpose + bf16 convert (vectorized) ----------------
__global__ __launch_bounds__(256)
void transpose_bf16_kernel(const float* __restrict__ src, ushort_t* __restrict__ dst,
                           int K, int N) {
    __shared__ float tile[64][65];
    const int i = blockIdx.z;
    const float* s = src + (size_t)i * K * N;
    ushort_t* d = dst + (size_t)i * K * N;
    const int t = threadIdx.x;
    const int rr = t >> 4;
    const int cc = t & 15;
    const int k0 = blockIdx.y * 64, n0 = blockIdx.x * 64;
#pragma unroll
    for (int r = 0; r < 4; ++r) {
        const int kr = rr + r * 16;
        const float4 v = *(const float4*)(s + (size_t)(k0 + kr) * N + n0 + cc * 4);
        tile[kr][cc * 4 + 0] = v.x;
        tile[kr][cc * 4 + 1] = v.y;
        tile[kr][cc * 4 + 2] = v.z;
        tile[kr][cc * 4 + 3] = v.w;
    }
    __syncthreads();
#pragma unroll
    for (int r = 0; r < 4; ++r) {
        const int nr = rr + r * 16;
        ushort4 o;
        o.x = f2bf(tile[cc * 4 + 0][nr]);
        o.y = f2bf(tile[cc * 4 + 1][nr]);
        o.z = f2bf(tile[cc * 4 + 2][nr]);
        o.w = f2bf(tile[cc * 4 + 3][nr]);
        *(ushort4*)(d + (size_t)(n0 + nr) * K + k0 + cc * 4) = o;
    }
}

// ---------------- seq-len kernel ----------------
__global__ __launch_bounds__(256)
void len_kernel(const int* __restrict__ mask, int* __restrict__ len) {
    const int wid = (blockIdx.x * 256 + threadIdx.x) >> 6;
    const int lane = threadIdx.x & 63;
    if (wid >= B_SZ) return;
    int c = (lane < SEQ) ? mask[(size_t)wid * SEQ + lane] : 0;
#pragma unroll
    for (int off = 32; off > 0; off >>= 1) c += __shfl_down(c, off);
    c = __shfl(c, 0);
    if (lane == 0) len[wid] = c;
}

// ---------------- raw-feature v3: aligned float2 LDS staging ----------------
// 2 rows per 256-thread block. Stage 10900 floats (2 contiguous rows,
// 8B-aligned) via coalesced float2 -> LDS; compute phase: thread (g,j)
// owns column j of row g, reads srow[g][s*109+j] (stride 109 = 2-way bank
// aliasing = free). Fixes the 4B-aligned 16B-load sector split of v2.
__global__ __launch_bounds__(256)
void rawfeat_kernel(const float* __restrict__ inp, const int* __restrict__ len,
                    float* __restrict__ hf, ushort_t* __restrict__ hb,
                    int* __restrict__ ids) {
    __shared__ float srow[2 * ROWLEN];
    const int tid = threadIdx.x;
    const int b0 = blockIdx.x * 2;

    // staging: 5450 float2 = 10900 floats, base 8B-aligned
    const float2* s2 = (const float2*)(inp + (size_t)b0 * ROWLEN);
    float2* l2 = (float2*)srow;
    for (int i = tid; i < ROWLEN; i += 256) l2[i] = s2[i];
    __syncthreads();

    const int g = tid >> 7;          // row within block (0/1)
    const int j = tid & 127;         // column index
    const int b = b0 + g;
    const int L = len[b];
    const float* my = srow + g * ROWLEN;
    const bool active = j < RAWF;

    float sum = 0.f, mx = -3.0e38f, mn = 3.0e38f, nxt = 0.f;
#pragma unroll 10
    for (int s = 0; s < SEQ; ++s) {
        const float v = active ? my[s * RAWF + j] : 0.f;
        if (j == 0) ids[(size_t)b * SEQ + s] = (int)v;
        if (s < L) { sum += v; mx = fmaxf(mx, v); mn = fminf(mn, v); }
        if (s == SEQ - 1) nxt = v;
    }
    if (j >= 1 && j < RAWF) {
        const int f = 19 + j;
        const float avg = sum / (float)L;
        mx = fminf(fmaxf(mx, 1e-9f), 1e9f);
        mn = fminf(fmaxf(mn, 1e-9f), 1e9f);
        const size_t base = (size_t)b * H;
        hf[base + f] = avg;             hb[base + f] = f2bf(avg);
        hf[base + DFEAT + f] = mx;      hb[base + DFEAT + f] = f2bf(mx);
        hf[base + 2 * DFEAT + f] = mn;  hb[base + 2 * DFEAT + f] = f2bf(mn);
        hf[base + 3 * DFEAT + f] = nxt; hb[base + 3 * DFEAT + f] = f2bf(nxt);
    }
}

// ---------------- embed-feature kernel ----------------
__global__ __launch_bounds__(256)
void embfeat_kernel(const int* __restrict__ ids, const int* __restrict__ len,
                    const float* __restrict__ embed,
                    float* __restrict__ hf, ushort_t* __restrict__ hb) {
    const int x = threadIdx.x & 31;
    const int row = (blockIdx.x * 256 + threadIdx.x) >> 5;
    if (row >= B_SZ) return;
    const int L = len[row];
    const int* idrow = ids + (size_t)row * SEQ;
    const bool act = x < EMB;
    float sum = 0.f, mx = -3.0e38f, mn = 3.0e38f, nxt = 0.f;
#pragma unroll 10
    for (int s = 0; s < SEQ; ++s) {
        const int id = idrow[s];
        const float v = act ? embed[(size_t)id * EMB + x] : 0.f;
        if (s < L) { sum += v; mx = fmaxf(mx, v); mn = fminf(mn, v); }
        if (s == SEQ - 1) nxt = v;
    }
    if (act) {
        const float avg = sum / (float)L;
        mx = fminf(fmaxf(mx, 1e-9f), 1e9f);
        mn = fminf(fmaxf(mn, 1e-9f), 1e9f);
        const size_t base = (size_t)row * H;
        hf[base + x] = avg;             hb[base + x] = f2bf(avg);
        hf[base + DFEAT + x] = mx;      hb[base + DFEAT + x] = f2bf(mx);
        hf[base + 2 * DFEAT + x] = mn;  hb[base + 2 * DFEAT + x] = f2bf(mn);
        hf[base + 3 * DFEAT + x] = nxt; hb[base + 3 * DFEAT + x] = f2bf(nxt);
    }
}

// ---------------- GEMM: C = relu(A(MxK) * Bt(NxK)^T + bias) ----------------
// 128x128 tile, BK=64, 4 waves, single-buffered m97-class structure
// (measured best: R10 config; all schedule variants neutral or regressed).
// MODE 0: write bf16 out. MODE 1: hf += relu(...); hb = bf16(hf)
template <int MODE>
__global__ __launch_bounds__(256, 3)
void gemm_kernel(const ushort_t* __restrict__ A, const ushort_t* __restrict__ Bt,
                 const float* __restrict__ bias,
                 ushort_t* __restrict__ outBf,
                 float* __restrict__ hf, ushort_t* __restrict__ hb,
                 int M, int N, int K) {
    __shared__ alignas(16) ushort_t lA[128 * 64];
    __shared__ alignas(16) ushort_t lB[128 * 64];
    const int tid = threadIdx.x;
    const int lane = tid & 63;
    const int w = tid >> 6;
    const int wm = w >> 1, wn = w & 1;

    const int gx = N >> 7;
    const int nwg = (M >> 7) * gx;
    const int cpx = nwg >> 3;
    const int bid = blockIdx.x;
    const int wg = (bid & 7) * cpx + (bid >> 3);
    const int ntile = wg % gx, mtile = wg / gx;

    const ushort_t* Abase = A + (size_t)mtile * 128 * K;
    const ushort_t* Bbase = Bt + (size_t)ntile * 128 * K;

    f32x4 acc[4][4];
#pragma unroll
    for (int a = 0; a < 4; ++a)
#pragma unroll
        for (int b = 0; b < 4; ++b) acc[a][b] = (f32x4)(0.f);

    const int l3 = lane >> 3;
    const int cl = (lane & 7) ^ l3;
    const int frow = lane & 15;
    const int k16b = lane >> 4;

    const int nkt = K >> 6;
    for (int kt = 0; kt < nkt; ++kt) {
#pragma unroll
        for (int it = 0; it < 4; ++it) {
            const int row = w * 32 + it * 8 + l3;
            const ushort_t* ga = Abase + (size_t)row * K + kt * 64 + cl * 8;
            const ushort_t* gb = Bbase + (size_t)row * K + kt * 64 + cl * 8;
            glds16(ga, lA + (w * 32 + it * 8) * 64);
            glds16(gb, lB + (w * 32 + it * 8) * 64);
        }
        asm volatile("s_waitcnt vmcnt(0)" ::: "memory");
        __syncthreads();

        bf16x8 af[4][2], bfg[4][2];
#pragma unroll
        for (int mf = 0; mf < 4; ++mf)
#pragma unroll
            for (int ks = 0; ks < 2; ++ks) {
                const int row = wm * 64 + mf * 16 + frow;
                const int c = (ks * 4 + k16b) ^ (row & 7);
                af[mf][ks] = *(const bf16x8*)(lA + row * 64 + c * 8);
            }
#pragma unroll
        for (int nf = 0; nf < 4; ++nf)
#pragma unroll
            for (int ks = 0; ks < 2; ++ks) {
                const int row = wn * 64 + nf * 16 + frow;
                const int c = (ks * 4 + k16b) ^ (row & 7);
                bfg[nf][ks] = *(const bf16x8*)(lB + row * 64 + c * 8);
            }
#pragma unroll
        for (int mf = 0; mf < 4; ++mf)
#pragma unroll
            for (int nf = 0; nf < 4; ++nf)
#pragma unroll
                for (int ks = 0; ks < 2; ++ks)
                    acc[mf][nf] = __builtin_amdgcn_mfma_f32_16x16x32_bf16(
                        af[mf][ks], bfg[nf][ks], acc[mf][nf], 0, 0, 0);
        __syncthreads();
    }

#pragma unroll
    for (int mf = 0; mf < 4; ++mf)
#pragma unroll
        for (int nf = 0; nf < 4; ++nf) {
            const int row0 = mtile * 128 + wm * 64 + mf * 16 + (lane >> 4) * 4;
            const int col = ntile * 128 + wn * 64 + nf * 16 + (lane & 15);
            const float bcol = bias[col];
#pragma unroll
            for (int jj = 0; jj < 4; ++jj) {
                float v = acc[mf][nf][jj] + bcol;
                v = v > 0.f ? v : 0.f;
                const size_t idx = (size_t)(row0 + jj) * N + col;
                if (MODE == 0) {
                    outBf[idx] = f2bf(v);
                } else {
                    float nh = hf[idx] + v;
                    hf[idx] = nh;
                    hb[idx] = f2bf(nh);
                }
            }
        }
}

// ---------------- final head ----------------
__global__ __launch_bounds__(256)
void final_kernel(const float* __restrict__ hf, const float* __restrict__ Wf,
                  const float* __restrict__ bfv, float* __restrict__ out) {
    const int gid = blockIdx.x * 256 + threadIdx.x;
    if (gid >= B_SZ * OUTD) return;
    const int b = gid / OUTD, o = gid % OUTD;
    const float* hrow = hf + (size_t)b * H;
    float acc = bfv[o];
    for (int k = 0; k < H; ++k) acc += hrow[k] * Wf[k * OUTD + o];
    out[gid] = acc;
}

extern "C" void kernel_launch(void* const* d_in, const int* in_sizes, int n_in,
                              void* d_out, int out_size, void* d_ws, size_t ws_size,
                              hipStream_t stream) {
    const float* inp   = (const float*)d_in[0];
    const int*   mask  = (const int*)d_in[1];
    const float* embed = (const float*)d_in[2];
    const float* W1    = (const float*)d_in[3];
    const float* b1    = (const float*)d_in[4];
    const float* W2    = (const float*)d_in[5];
    const float* b2    = (const float*)d_in[6];
    const float* Wf    = (const float*)d_in[7];
    const float* bfv   = (const float*)d_in[8];
    float* out = (float*)d_out;

    char* ws = (char*)d_ws;
    ushort_t* W1t = (ushort_t*)ws;
    ushort_t* W2t = W1t + (size_t)NBLK * H4 * H;
    float*    hf  = (float*)(W2t + (size_t)NBLK * H * H4);
    ushort_t* hb  = (ushort_t*)(hf + (size_t)B_SZ * H);
    ushort_t* T   = hb + (size_t)B_SZ * H;
    int* ids = (int*)T;
    int* lenb = ids + (size_t)B_SZ * SEQ;

    transpose_bf16_kernel<<<dim3(H4 / 64, H / 64, NBLK), 256, 0, stream>>>(W1, W1t, H, H4);
    transpose_bf16_kernel<<<dim3(H / 64, H4 / 64, NBLK), 256, 0, stream>>>(W2, W2t, H4, H);

    len_kernel<<<(B_SZ * 64 + 255) / 256, 256, 0, stream>>>(mask, lenb);
    rawfeat_kernel<<<B_SZ / 2, 256, 0, stream>>>(inp, lenb, hf, hb, ids);
    embfeat_kernel<<<(B_SZ * 32 + 255) / 256, 256, 0, stream>>>(ids, lenb, embed, hf, hb);

    for (int i = 0; i < NBLK; ++i) {
        gemm_kernel<0><<<(B_SZ / 128) * (H4 / 128), 256, 0, stream>>>(
            hb, W1t + (size_t)i * H4 * H, b1 + (size_t)i * H4, T, nullptr, nullptr,
            B_SZ, H4, H);
        gemm_kernel<1><<<(B_SZ / 128) * (H / 128), 256, 0, stream>>>(
            T, W2t + (size_t)i * H * H4, b2 + (size_t)i * H, nullptr, hf, hb,
            B_SZ, H, H4);
    }

    final_kernel<<<(B_SZ * OUTD + 255) / 256, 256, 0, stream>>>(hf, Wf, bfv, out);
}

// Round 15
// 1245.841 us; speedup vs baseline: 1.0619x; 1.0619x over previous
//
#include <hip/hip_runtime.h>
#include <stdint.h>

typedef unsigned short ushort_t;
typedef __attribute__((ext_vector_type(8))) __bf16 bf16x8;
typedef __attribute__((ext_vector_type(4))) float f32x4;
typedef float f32x4u __attribute__((ext_vector_type(4), aligned(4)));

#define B_SZ 16384
#define SEQ 50
#define RAWF 109
#define EMB 20
#define DFEAT 128
#define H 512
#define H4 2048
#define NBLK 10
#define OUTD 20

__device__ __forceinline__ ushort_t f2bf(float f) {
    union { float f; uint32_t u; } v; v.f = f;
    uint32_t r = (v.u + 0x7fffu + ((v.u >> 16) & 1u)) >> 16;
    return (ushort_t)r;
}

__device__ __forceinline__ void glds16(const ushort_t* src, ushort_t* dst) {
    __builtin_amdgcn_global_load_lds(
        (const __attribute__((address_space(1))) void*)src,
        (__attribute__((address_space(3))) void*)dst, 16, 0, 0);
}

// ---------------- weight transpose + bf16 convert (vectorized) ----------------
__global__ __launch_bounds__(256)
void transpose_bf16_kernel(const float* __restrict__ src, ushort_t* __restrict__ dst,
                           int K, int N) {
    __shared__ float tile[64][65];
    const int i = blockIdx.z;
    const float* s = src + (size_t)i * K * N;
    ushort_t* d = dst + (size_t)i * K * N;
    const int t = threadIdx.x;
    const int rr = t >> 4;
    const int cc = t & 15;
    const int k0 = blockIdx.y * 64, n0 = blockIdx.x * 64;
#pragma unroll
    for (int r = 0; r < 4; ++r) {
        const int kr = rr + r * 16;
        const float4 v = *(const float4*)(s + (size_t)(k0 + kr) * N + n0 + cc * 4);
        tile[kr][cc * 4 + 0] = v.x;
        tile[kr][cc * 4 + 1] = v.y;
        tile[kr][cc * 4 + 2] = v.z;
        tile[kr][cc * 4 + 3] = v.w;
    }
    __syncthreads();
#pragma unroll
    for (int r = 0; r < 4; ++r) {
        const int nr = rr + r * 16;
        ushort4 o;
        o.x = f2bf(tile[cc * 4 + 0][nr]);
        o.y = f2bf(tile[cc * 4 + 1][nr]);
        o.z = f2bf(tile[cc * 4 + 2][nr]);
        o.w = f2bf(tile[cc * 4 + 3][nr]);
        *(ushort4*)(d + (size_t)(n0 + nr) * K + k0 + cc * 4) = o;
    }
}

// ---------------- seq-len kernel ----------------
__global__ __launch_bounds__(256)
void len_kernel(const int* __restrict__ mask, int* __restrict__ len) {
    const int wid = (blockIdx.x * 256 + threadIdx.x) >> 6;
    const int lane = threadIdx.x & 63;
    if (wid >= B_SZ) return;
    int c = (lane < SEQ) ? mask[(size_t)wid * SEQ + lane] : 0;
#pragma unroll
    for (int off = 32; off > 0; off >>= 1) c += __shfl_down(c, off);
    c = __shfl(c, 0);
    if (lane == 0) len[wid] = c;
}

// ---------------- raw-feature kernel v2: float4 over feature axis ----------
// Measured best (R10): register-direct, 32 lanes/row, 8 rows/block.
__global__ __launch_bounds__(256)
void rawfeat_kernel(const float* __restrict__ inp, const int* __restrict__ len,
                    float* __restrict__ hf, ushort_t* __restrict__ hb,
                    int* __restrict__ ids) {
    const int g = threadIdx.x >> 5;
    const int q = threadIdx.x & 31;
    const int b = blockIdx.x * 8 + g;
    const float* src = inp + (size_t)b * SEQ * RAWF;
    const int L = len[b];
    const int c0 = q * 4;
    f32x4u sum = (f32x4u)(0.f);
    f32x4u mx = (f32x4u)(-3.0e38f);
    f32x4u mn = (f32x4u)(3.0e38f);
    f32x4u nxt = (f32x4u)(0.f);
#pragma unroll 5
    for (int s = 0; s < SEQ; ++s) {
        f32x4u v = (f32x4u)(0.f);
        if (q < 27) {
            v = *(const f32x4u*)(src + s * RAWF + c0);
        } else if (q == 27) {
            v.x = src[s * RAWF + 108];
        }
        if (q == 0) ids[(size_t)b * SEQ + s] = (int)v.x;
        if (s < L) {
            sum += v;
            mx.x = fmaxf(mx.x, v.x); mx.y = fmaxf(mx.y, v.y);
            mx.z = fmaxf(mx.z, v.z); mx.w = fmaxf(mx.w, v.w);
            mn.x = fminf(mn.x, v.x); mn.y = fminf(mn.y, v.y);
            mn.z = fminf(mn.z, v.z); mn.w = fminf(mn.w, v.w);
        }
        if (s == SEQ - 1) nxt = v;
    }
    if (q < 28) {
        const float rinv = 1.0f / (float)L;
        const size_t base = (size_t)b * H;
#pragma unroll
        for (int e = 0; e < 4; ++e) {
            const int c = c0 + e;
            if (c < 1 || c > 108) continue;
            const int j = 19 + c;
            const float a = sum[e] * rinv;
            const float mxe = fminf(fmaxf(mx[e], 1e-9f), 1e9f);
            const float mne = fminf(fmaxf(mn[e], 1e-9f), 1e9f);
            const float nx = nxt[e];
            hf[base + j] = a;               hb[base + j] = f2bf(a);
            hf[base + DFEAT + j] = mxe;     hb[base + DFEAT + j] = f2bf(mxe);
            hf[base + 2 * DFEAT + j] = mne; hb[base + 2 * DFEAT + j] = f2bf(mne);
            hf[base + 3 * DFEAT + j] = nx;  hb[base + 3 * DFEAT + j] = f2bf(nx);
        }
    }
}

// ---------------- embed-feature kernel ----------------
__global__ __launch_bounds__(256)
void embfeat_kernel(const int* __restrict__ ids, const int* __restrict__ len,
                    const float* __restrict__ embed,
                    float* __restrict__ hf, ushort_t* __restrict__ hb) {
    const int x = threadIdx.x & 31;
    const int row = (blockIdx.x * 256 + threadIdx.x) >> 5;
    if (row >= B_SZ) return;
    const int L = len[row];
    const int* idrow = ids + (size_t)row * SEQ;
    const bool act = x < EMB;
    float sum = 0.f, mx = -3.0e38f, mn = 3.0e38f, nxt = 0.f;
#pragma unroll 10
    for (int s = 0; s < SEQ; ++s) {
        const int id = idrow[s];
        const float v = act ? embed[(size_t)id * EMB + x] : 0.f;
        if (s < L) { sum += v; mx = fmaxf(mx, v); mn = fminf(mn, v); }
        if (s == SEQ - 1) nxt = v;
    }
    if (act) {
        const float avg = sum / (float)L;
        mx = fminf(fmaxf(mx, 1e-9f), 1e9f);
        mn = fminf(fmaxf(mn, 1e-9f), 1e9f);
        const size_t base = (size_t)row * H;
        hf[base + x] = avg;             hb[base + x] = f2bf(avg);
        hf[base + DFEAT + x] = mx;      hb[base + DFEAT + x] = f2bf(mx);
        hf[base + 2 * DFEAT + x] = mn;  hb[base + 2 * DFEAT + x] = f2bf(mn);
        hf[base + 3 * DFEAT + x] = nxt; hb[base + 3 * DFEAT + x] = f2bf(nxt);
    }
}

// ---------------- GEMM: C = relu(A(MxK) * Bt(NxK)^T + bias) ----------------
// Measured-best config (R10): 128x128 tile, BK=64, 4 waves, single-buffered,
// __launch_bounds__(256,3), XCD-aware swizzle.
// MODE 0: write bf16 out. MODE 1: hf += relu(...); hb = bf16(hf)
template <int MODE>
__global__ __launch_bounds__(256, 3)
void gemm_kernel(const ushort_t* __restrict__ A, const ushort_t* __restrict__ Bt,
                 const float* __restrict__ bias,
                 ushort_t* __restrict__ outBf,
                 float* __restrict__ hf, ushort_t* __restrict__ hb,
                 int M, int N, int K) {
    __shared__ alignas(16) ushort_t lA[128 * 64];
    __shared__ alignas(16) ushort_t lB[128 * 64];
    const int tid = threadIdx.x;
    const int lane = tid & 63;
    const int w = tid >> 6;
    const int wm = w >> 1, wn = w & 1;

    const int gx = N >> 7;
    const int nwg = (M >> 7) * gx;
    const int cpx = nwg >> 3;
    const int bid = blockIdx.x;
    const int wg = (bid & 7) * cpx + (bid >> 3);
    const int ntile = wg % gx, mtile = wg / gx;

    const ushort_t* Abase = A + (size_t)mtile * 128 * K;
    const ushort_t* Bbase = Bt + (size_t)ntile * 128 * K;

    f32x4 acc[4][4];
#pragma unroll
    for (int a = 0; a < 4; ++a)
#pragma unroll
        for (int b = 0; b < 4; ++b) acc[a][b] = (f32x4)(0.f);

    const int l3 = lane >> 3;
    const int cl = (lane & 7) ^ l3;
    const int frow = lane & 15;
    const int k16b = lane >> 4;

    const int nkt = K >> 6;
    for (int kt = 0; kt < nkt; ++kt) {
#pragma unroll
        for (int it = 0; it < 4; ++it) {
            const int row = w * 32 + it * 8 + l3;
            const ushort_t* ga = Abase + (size_t)row * K + kt * 64 + cl * 8;
            const ushort_t* gb = Bbase + (size_t)row * K + kt * 64 + cl * 8;
            glds16(ga, lA + (w * 32 + it * 8) * 64);
            glds16(gb, lB + (w * 32 + it * 8) * 64);
        }
        asm volatile("s_waitcnt vmcnt(0)" ::: "memory");
        __syncthreads();

        bf16x8 af[4][2], bfg[4][2];
#pragma unroll
        for (int mf = 0; mf < 4; ++mf)
#pragma unroll
            for (int ks = 0; ks < 2; ++ks) {
                const int row = wm * 64 + mf * 16 + frow;
                const int c = (ks * 4 + k16b) ^ (row & 7);
                af[mf][ks] = *(const bf16x8*)(lA + row * 64 + c * 8);
            }
#pragma unroll
        for (int nf = 0; nf < 4; ++nf)
#pragma unroll
            for (int ks = 0; ks < 2; ++ks) {
                const int row = wn * 64 + nf * 16 + frow;
                const int c = (ks * 4 + k16b) ^ (row & 7);
                bfg[nf][ks] = *(const bf16x8*)(lB + row * 64 + c * 8);
            }
#pragma unroll
        for (int mf = 0; mf < 4; ++mf)
#pragma unroll
            for (int nf = 0; nf < 4; ++nf)
#pragma unroll
                for (int ks = 0; ks < 2; ++ks)
                    acc[mf][nf] = __builtin_amdgcn_mfma_f32_16x16x32_bf16(
                        af[mf][ks], bfg[nf][ks], acc[mf][nf], 0, 0, 0);
        __syncthreads();
    }

#pragma unroll
    for (int mf = 0; mf < 4; ++mf)
#pragma unroll
        for (int nf = 0; nf < 4; ++nf) {
            const int row0 = mtile * 128 + wm * 64 + mf * 16 + (lane >> 4) * 4;
            const int col = ntile * 128 + wn * 64 + nf * 16 + (lane & 15);
            const float bcol = bias[col];
#pragma unroll
            for (int jj = 0; jj < 4; ++jj) {
                float v = acc[mf][nf][jj] + bcol;
                v = v > 0.f ? v : 0.f;
                const size_t idx = (size_t)(row0 + jj) * N + col;
                if (MODE == 0) {
                    outBf[idx] = f2bf(v);
                } else {
                    float nh = hf[idx] + v;
                    hf[idx] = nh;
                    hb[idx] = f2bf(nh);
                }
            }
        }
}

// ---------------- final head ----------------
__global__ __launch_bounds__(256)
void final_kernel(const float* __restrict__ hf, const float* __restrict__ Wf,
                  const float* __restrict__ bfv, float* __restrict__ out) {
    const int gid = blockIdx.x * 256 + threadIdx.x;
    if (gid >= B_SZ * OUTD) return;
    const int b = gid / OUTD, o = gid % OUTD;
    const float* hrow = hf + (size_t)b * H;
    float acc = bfv[o];
    for (int k = 0; k < H; ++k) acc += hrow[k] * Wf[k * OUTD + o];
    out[gid] = acc;
}

extern "C" void kernel_launch(void* const* d_in, const int* in_sizes, int n_in,
                              void* d_out, int out_size, void* d_ws, size_t ws_size,
                              hipStream_t stream) {
    const float* inp   = (const float*)d_in[0];
    const int*   mask  = (const int*)d_in[1];
    const float* embed = (const float*)d_in[2];
    const float* W1    = (const float*)d_in[3];
    const float* b1    = (const float*)d_in[4];
    const float* W2    = (const float*)d_in[5];
    const float* b2    = (const float*)d_in[6];
    const float* Wf    = (const float*)d_in[7];
    const float* bfv   = (const float*)d_in[8];
    float* out = (float*)d_out;

    char* ws = (char*)d_ws;
    ushort_t* W1t = (ushort_t*)ws;
    ushort_t* W2t = W1t + (size_t)NBLK * H4 * H;
    float*    hf  = (float*)(W2t + (size_t)NBLK * H * H4);
    ushort_t* hb  = (ushort_t*)(hf + (size_t)B_SZ * H);
    ushort_t* T   = hb + (size_t)B_SZ * H;
    int* ids = (int*)T;
    int* lenb = ids + (size_t)B_SZ * SEQ;

    transpose_bf16_kernel<<<dim3(H4 / 64, H / 64, NBLK), 256, 0, stream>>>(W1, W1t, H, H4);
    transpose_bf16_kernel<<<dim3(H / 64, H4 / 64, NBLK), 256, 0, stream>>>(W2, W2t, H4, H);

    len_kernel<<<(B_SZ * 64 + 255) / 256, 256, 0, stream>>>(mask, lenb);
    rawfeat_kernel<<<B_SZ / 8, 256, 0, stream>>>(inp, lenb, hf, hb, ids);
    embfeat_kernel<<<(B_SZ * 32 + 255) / 256, 256, 0, stream>>>(ids, lenb, embed, hf, hb);

    for (int i = 0; i < NBLK; ++i) {
        gemm_kernel<0><<<(B_SZ / 128) * (H4 / 128), 256, 0, stream>>>(
            hb, W1t + (size_t)i * H4 * H, b1 + (size_t)i * H4, T, nullptr, nullptr,
            B_SZ, H4, H);
        gemm_kernel<1><<<(B_SZ / 128) * (H / 128), 256, 0, stream>>>(
            T, W2t + (size_t)i * H * H4, b2 + (size_t)i * H, nullptr, hf, hb,
            B_SZ, H, H4);
    }

    final_kernel<<<(B_SZ * OUTD + 255) / 256, 256, 0, stream>>>(hf, Wf, bfv, out);
}